// Round 3
// baseline (779.808 us; speedup 1.0000x reference)
//
#include <hip/hip_runtime.h>
#include <cfloat>
#include <math.h>

namespace {
constexpr int Bn = 4, Cin = 8, Pn = 12000, Nn = 64, Co = 64, Hh = 282, Ww = 282;
constexpr int NPIL  = Bn * Pn;
constexpr int NCELL = Hh * Ww;
constexpr int CHW   = Pn * Nn;
constexpr double CNTD = (double)Bn * Pn * Nn;
constexpr int K1B = 256;
constexpr int WL_CAP = 48000;           // max occupied cells per input (12000 x 4 batches)
constexpr int APPLY_B = (WL_CAP + 255) / 256;

constexpr size_t PAR_OFF  = 0;
constexpr size_t MOM_OFF  = 2048;
constexpr size_t HDR_OFF  = 2816;
constexpr size_t WIN_OFF  = 4096;
constexpr size_t FEAT_OFF = 2548864;
constexpr size_t PART_OFF = FEAT_OFF + 24576000;
constexpr size_t WLS_OFF  = PART_OFF + (size_t)K1B * 88 * 4;
constexpr size_t WLM_OFF  = WLS_OFF + (size_t)WL_CAP * 8;
constexpr size_t WS_NEED  = WLM_OFF + (size_t)WL_CAP * 8;

// Grid mapping matched to XLA's canonicalization: division by 0.16 becomes
// multiplication by the EXACT reciprocal 6.25 (rcp(0.16f) rounds to 6.25f).
// f32-div differs by ~0.3ulp -> O(1) pillars land one cell off (the 2.62 bug).
__device__ __forceinline__ int cell_of(float xc, float yc) {
  int xg = (int)floorf((xc + 22.0f) * 6.25f);
  int yg = (int)floorf((yc + 22.0f) * 6.25f);
  xg = min(max(xg, 0), Ww - 1);
  yg = min(max(yg, 0), Hh - 1);
  return yg * Ww + xg;
}

__device__ __forceinline__ float firstlane(float v) {
  return __int_as_float(__builtin_amdgcn_readfirstlane(__float_as_int(v)));
}
}

__global__ void kdiag(float* __restrict__ out, float v) {
  if (threadIdx.x == 0 && blockIdx.x == 0) out[0] = v;
}

__global__ void k0_init(int* __restrict__ winners, int* __restrict__ hdr) {
  const int stride = gridDim.x * blockDim.x;
  const int t = blockIdx.x * blockDim.x + threadIdx.x;
  if (t < 4) hdr[t] = 0;
  for (int i = t; i < 2 * Bn * NCELL; i += stride) winners[i] = -1;
}

// Merged over both inputs: blocks [0,K1B) -> sweep, [K1B,2*K1B) -> map.
// Per-input wave decomposition identical to the split version -> bit-identical
// partial sums -> bit-identical moments. The pillar->cell scatter is fused in
// (lane 0 already holds xc/yc): one atomicMax per pillar, off the hot path.
__global__ __launch_bounds__(256) void k1_mom(
    const float* __restrict__ sweep, const float* __restrict__ map_in,
    float* __restrict__ partOut, int* __restrict__ winners)
{
  __shared__ float red[4][44];
  const int lane = threadIdx.x & 63;
  const int wv   = threadIdx.x >> 6;
  const int bid2 = blockIdx.x & (K1B - 1);
  const int inp  = blockIdx.x >> 8;
  const float* x = inp ? map_in : sweep;
  int* win = winners + inp * Bn * NCELL;
  const int gw   = (bid2 * 256 + (int)threadIdx.x) >> 6;
  const int nw   = (K1B * 256) >> 6;

  float sacc[8];
  float macc[36];
#pragma unroll
  for (int i = 0; i < 8; ++i) sacc[i] = 0.f;
#pragma unroll
  for (int i = 0; i < 36; ++i) macc[i] = 0.f;

  for (int pp = gw; pp < NPIL; pp += nw) {
    const int b = pp / Pn;
    const int p = pp - b * Pn;
    const float* xb = x + (size_t)b * Cin * CHW + (size_t)p * Nn + lane;
    float xv[Cin];
#pragma unroll
    for (int c = 0; c < Cin; ++c) xv[c] = xb[(size_t)c * CHW];
#pragma unroll
    for (int c = 0; c < Cin; ++c) sacc[c] += xv[c];
    {
      int k = 0;
#pragma unroll
      for (int i = 0; i < 8; ++i)
#pragma unroll
        for (int j = i; j < 8; ++j) { macc[k] = fmaf(xv[i], xv[j], macc[k]); ++k; }
    }
    // Fused scatter: xc = x[base] = lane 0's xv[0], yc = lane 0's xv[1].
    const float xc = firstlane(xv[0]);
    if (xc != 0.0f) {
      const float yc = firstlane(xv[1]);
      if (lane == 0) atomicMax(&win[b * NCELL + cell_of(xc, yc)], p);
    }
  }

#pragma unroll
  for (int k = 0; k < 44; ++k) {
    float v = (k < 8) ? sacc[k] : macc[k - 8];
#pragma unroll
    for (int off = 32; off > 0; off >>= 1) v += __shfl_down(v, off, 64);
    if (lane == 0) red[wv][k] = v;
  }
  __syncthreads();
  if (threadIdx.x < 44) {
    const float s = red[0][threadIdx.x] + red[1][threadIdx.x] +
                    red[2][threadIdx.x] + red[3][threadIdx.x];
    partOut[(size_t)bid2 * 88 + inp * 44 + threadIdx.x] = s;
  }
}

__global__ void k1b_reduce(const float* __restrict__ part, double* __restrict__ mom)
{
  const int t = threadIdx.x;
  if (t >= 88) return;
  double s = 0.0;
  for (int blk = 0; blk < K1B; ++blk) s += (double)part[(size_t)blk * 88 + t];
  mom[t] = s;
}

__global__ void k2_params(const double* __restrict__ mom,
    const float* __restrict__ w_s, const float* __restrict__ b_s,
    const float* __restrict__ g_s, const float* __restrict__ be_s,
    const float* __restrict__ w_m, const float* __restrict__ b_m,
    const float* __restrict__ g_m, const float* __restrict__ be_m,
    float* __restrict__ par)
{
  const int t = threadIdx.x;
  if (t >= 128) return;
  const int inp = t >> 6, o = t & 63;
  const double* m = mom + inp * 44;
  const float* w    = (inp ? w_m : w_s) + o * Cin;
  const float bias  = (inp ? b_m : b_s)[o];
  const float gamma = (inp ? g_m : g_s)[o];
  const float beta  = (inp ? be_m : be_s)[o];
  double S[8];
#pragma unroll
  for (int c = 0; c < 8; ++c) S[c] = m[c] / CNTD;
  double mean = (double)bias;
#pragma unroll
  for (int c = 0; c < 8; ++c) mean += (double)w[c] * S[c];
  double var = 0.0;
  int k = 8;
#pragma unroll
  for (int i = 0; i < 8; ++i)
#pragma unroll
    for (int j = i; j < 8; ++j) {
      const double cov = m[k] / CNTD - S[i] * S[j];
      const double ww = (double)w[i] * (double)w[j];
      var += (i == j ? ww : 2.0 * ww) * cov;
      ++k;
    }
  const double a = (double)gamma / sqrt(var + 1e-5);
  const double c = (double)beta - mean * a;
  par[inp * 128 + o]      = (float)a;
  par[inp * 128 + 64 + o] = (float)c;
}

// Build packed worklists of occupied cells so the backbone matvec runs on
// dense waves. Entry = {outbase = b*Co*NCELL + hw, featrow = b*Pn + p}.
// hdr[1]/hdr[2] counts double as the occupancy diagnostic (old k3b).
__global__ void k_compact(const int* __restrict__ winners, int* __restrict__ hdr,
                          int2* __restrict__ wlS, int2* __restrict__ wlM)
{
  const int t = blockIdx.x * blockDim.x + threadIdx.x;
  if (t >= Bn * NCELL) return;
  const int b = t / NCELL;
  const int hw = t - b * NCELL;
  const int outbase = b * Co * NCELL + hw;
  const int ps = winners[t];
  const int pm = winners[Bn * NCELL + t];
  if (ps >= 0) {
    const int pos = atomicAdd(&hdr[1], 1);
    wlS[pos] = make_int2(outbase, b * Pn + ps);
  }
  if (pm >= 0) {
    const int pos = atomicAdd(&hdr[2], 1);
    wlM[pos] = make_int2(outbase, b * Pn + pm);
  }
}

// Transposed PFN: one pillar per wave, lane = point index n (not channel).
// xv[c] is lane-local -> the o-loop is pure fma with wave-UNIFORM (scalar)
// weight/bias/par operands: no broadcasts on the VALU path at all.
// z[o] = fmaf(a[o], y(o,n), cc[o]) is the same fma chain as before per (o,n).
// The max over n becomes a 6-round butterfly reduce-scatter across lanes:
// round m pairs registers (i, i+m); lane keeps the half matching its bit m
// and receives the partner's half. After 6 rounds lane l holds exactly
// channel l's max -- fmax is exact under reordering -> bit-identical.
__global__ __launch_bounds__(256) void k5f_feat(
    const float* __restrict__ sweep, const float* __restrict__ map_in,
    const float* __restrict__ w_s, const float* __restrict__ b_s,
    const float* __restrict__ w_m, const float* __restrict__ b_m,
    const float* __restrict__ par, const int* __restrict__ winners,
    float* __restrict__ feats)
{
  const int lane = threadIdx.x & 63;       // = n
  const int wv   = threadIdx.x >> 6;
  int pp = blockIdx.x * 4 + wv;
  const int inp = (pp >= NPIL) ? 1 : 0;
  pp -= inp * NPIL;
  const float* x    = inp ? map_in : sweep;
  const float* w    = inp ? w_m : w_s;
  const float* bias = inp ? b_m : b_s;
  const float* pr   = par + inp * 128;
  const int*   win  = winners + inp * Bn * NCELL;
  float*       ft   = feats + (size_t)inp * NPIL * 64;

  const int b = pp / Pn;
  const int p = pp - b * Pn;
  const size_t base = (size_t)b * Cin * CHW + (size_t)p * Nn;

  float xv[Cin];
#pragma unroll
  for (int c = 0; c < Cin; ++c) xv[c] = x[base + (size_t)c * CHW + lane];

  const float xc0 = firstlane(xv[0]);
  if (xc0 == 0.0f) return;
  const float yc0 = firstlane(xv[1]);
  const int cell = cell_of(xc0, yc0);
  if (win[b * NCELL + cell] != p) return;

  float z[64];
#pragma unroll
  for (int o = 0; o < 64; ++o) {
    float y = bias[o];
#pragma unroll
    for (int c = 0; c < Cin; ++c) y = fmaf(w[o * Cin + c], xv[c], y);
    z[o] = fmaf(pr[o], y, pr[64 + o]);
  }

  // Butterfly reduce-scatter max: after round m, z[0..m) live; lane l ends
  // holding max over all 64 lanes of original z[l].
#pragma unroll
  for (int m = 32; m >= 1; m >>= 1) {
    const bool hi = (lane & m) != 0;
#pragma unroll
    for (int i = 0; i < m; ++i) {
      const float send = hi ? z[i] : z[i + m];
      const float recv = __shfl_xor(send, m, 64);
      const float keep = hi ? z[i + m] : z[i];
      z[i] = fmaxf(keep, recv);
    }
  }

  ft[(size_t)pp * 64 + lane] = fmaxf(z[0], 0.f);
}

// Fill the whole output with bias (pure coalesced float4 writes).
// Grid is exact: Bn*Co*NCELL/4 = 19881*256 threads, one float4 each.
__global__ __launch_bounds__(256) void k_fill(const float* __restrict__ b_bb,
                                              float* __restrict__ out)
{
  const int idx = blockIdx.x * 256 + threadIdx.x;
  const int plane = idx / (NCELL / 4);      // b*Co + o
  const float v = b_bb[plane & 63];
  ((float4*)out)[idx] = make_float4(v, v, v, v);
}

// Dense matvec over the compacted worklist.
// WHICH=0 (sweep): out[o] = bias[o] + W[:,0:64]·f   (overwrite after k_fill)
// WHICH=1 (map):   out[o] +=          W[:,64:128]·f (RMW, runs after WHICH=0)
// fmaf ordering is identical to the fused version -> bit-identical output.
template<int WHICH>
__global__ __launch_bounds__(256) void k_apply(
    const int* __restrict__ hdr, const int2* __restrict__ wl,
    const float* __restrict__ feats, const float* __restrict__ w_bb,
    const float* __restrict__ b_bb, float* __restrict__ out)
{
  __shared__ float4 wlds[Co * 16];
  __shared__ float bbb[Co];
  for (int i = threadIdx.x; i < Co * 16; i += 256)
    wlds[i] = ((const float4*)w_bb)[((i >> 4) << 5) + (WHICH ? 16 : 0) + (i & 15)];
  if (threadIdx.x < Co) bbb[threadIdx.x] = b_bb[threadIdx.x];
  __syncthreads();
  const int cnt = hdr[1 + WHICH];
  for (int i = blockIdx.x * blockDim.x + threadIdx.x; i < cnt;
       i += gridDim.x * blockDim.x) {
    const int2 e = wl[i];
    const float4* fp = (const float4*)(feats + (size_t)e.y * 64);
    float4 f[16];
#pragma unroll
    for (int k = 0; k < 16; ++k) f[k] = fp[k];
    float* op = out + e.x;
#pragma unroll 2
    for (int o = 0; o < Co; ++o) {
      float acc = WHICH ? op[(size_t)o * NCELL] : bbb[o];
      const float4* row = &wlds[o * 16];
#pragma unroll
      for (int k = 0; k < 16; ++k) {
        const float4 w4 = row[k];
        acc = fmaf(w4.x, f[k].x, acc); acc = fmaf(w4.y, f[k].y, acc);
        acc = fmaf(w4.z, f[k].z, acc); acc = fmaf(w4.w, f[k].w, acc);
      }
      op[(size_t)o * NCELL] = acc;
    }
  }
}

__global__ void k6_verdict(const int* __restrict__ hdr, float* __restrict__ out)
{
  if (threadIdx.x != 0 || blockIdx.x != 0) return;
  const int n_occ = hdr[1] + hdr[2];
  if (n_occ < 80000 || n_occ > 96000) out[0] = 1.0e7f + (float)n_occ;
}

extern "C" void kernel_launch(void* const* d_in, const int* in_sizes, int n_in,
                              void* d_out, int out_size, void* d_ws, size_t ws_size,
                              hipStream_t stream)
{
  const float* sweep  = (const float*)d_in[0];
  const float* map_in = (const float*)d_in[1];
  const float* w_s  = (const float*)d_in[2];
  const float* b_s  = (const float*)d_in[3];
  const float* g_s  = (const float*)d_in[4];
  const float* be_s = (const float*)d_in[5];
  const float* w_m  = (const float*)d_in[6];
  const float* b_m  = (const float*)d_in[7];
  const float* g_m  = (const float*)d_in[8];
  const float* be_m = (const float*)d_in[9];
  const float* w_bb = (const float*)d_in[10];
  const float* b_bb = (const float*)d_in[11];
  float* out = (float*)d_out;

  const int exp_sz[12] = {24576000, 24576000, 512, 64, 64, 64, 512, 64, 64, 64, 8192, 64};
  int bad_idx = -1;
  if (n_in != 12) bad_idx = 11;
  else for (int i = 0; i < 12; ++i) if (in_sizes[i] != exp_sz[i]) { bad_idx = i; break; }
  if (bad_idx >= 0) {
    kdiag<<<1, 1, 0, stream>>>(out, 9.0e7f + 1.0e5f * (float)bad_idx);
    return;
  }
  if (ws_size < WS_NEED) {
    kdiag<<<1, 1, 0, stream>>>(out, 8.0e7f);
    return;
  }

  char* ws = (char*)d_ws;
  float*  par     = (float*)(ws + PAR_OFF);
  double* mom     = (double*)(ws + MOM_OFF);
  int*    hdr     = (int*)(ws + HDR_OFF);
  int*    winners = (int*)(ws + WIN_OFF);
  float*  feats   = (float*)(ws + FEAT_OFF);
  float*  part    = (float*)(ws + PART_OFF);
  int2*   wlS     = (int2*)(ws + WLS_OFF);
  int2*   wlM     = (int2*)(ws + WLM_OFF);

  k0_init<<<512, 256, 0, stream>>>(winners, hdr);
  k_fill<<<(Bn * Co * NCELL / 4) / 256, 256, 0, stream>>>(b_bb, out);
  k1_mom<<<2 * K1B, 256, 0, stream>>>(sweep, map_in, part, winners);
  k1b_reduce<<<1, 128, 0, stream>>>(part, mom);
  k2_params<<<1, 128, 0, stream>>>(mom, w_s, b_s, g_s, be_s, w_m, b_m, g_m, be_m, par);
  k_compact<<<(Bn * NCELL + 255) / 256, 256, 0, stream>>>(winners, hdr, wlS, wlM);
  k5f_feat<<<2 * NPIL / 4, 256, 0, stream>>>(sweep, map_in, w_s, b_s, w_m, b_m,
                                             par, winners, feats);
  k_apply<0><<<APPLY_B, 256, 0, stream>>>(hdr, wlS, feats, w_bb, b_bb, out);
  k_apply<1><<<APPLY_B, 256, 0, stream>>>(hdr, wlM, feats + (size_t)NPIL * 64,
                                          w_bb, b_bb, out);
  k6_verdict<<<1, 1, 0, stream>>>(hdr, out);
}

// Round 4
// 567.883 us; speedup vs baseline: 1.3732x; 1.3732x over previous
//
#include <hip/hip_runtime.h>
#include <cfloat>
#include <math.h>

namespace {
constexpr int Bn = 4, Cin = 8, Pn = 12000, Nn = 64, Co = 64, Hh = 282, Ww = 282;
constexpr int NPIL  = Bn * Pn;
constexpr int NCELL = Hh * Ww;
constexpr int CHW   = Pn * Nn;
constexpr double CNTD = (double)Bn * Pn * Nn;
constexpr int K1B = 1024;               // k1_mom blocks per input (8 waves/SIMD)
constexpr int WL_CAP = 48000;           // max occupied cells per input
constexpr int APPLY_B = (WL_CAP + 255) / 256;

// Workspace layout. part (k1_mom partials) aliases the feats region: it is
// dead after k1b_reduce, before k5f_feat writes feats.
constexpr size_t PAR_OFF  = 0;                          // 2*576 floats = 4608
constexpr size_t MOM_OFF  = 4608;                       // 88 doubles   = 704
constexpr size_t HDR_OFF  = 5376;                       // 4 ints
constexpr size_t WLS_OFF  = 8192;                       // WL_CAP int2
constexpr size_t WLM_OFF  = WLS_OFF + (size_t)WL_CAP * 8;
constexpr size_t WIN_OFF  = WLM_OFF + (size_t)WL_CAP * 8;   // 776192
constexpr size_t FEAT_OFF = WIN_OFF + (size_t)2 * Bn * NCELL * 4; // 3320960
constexpr size_t PART_OFF = FEAT_OFF;                   // alias (see above)
constexpr size_t WS_NEED  = FEAT_OFF + (size_t)2 * NPIL * 64 * 4; // 27896960

// Grid mapping matched to XLA's canonicalization: division by 0.16 becomes
// multiplication by the EXACT reciprocal 6.25 (rcp(0.16f) rounds to 6.25f).
// f32-div differs by ~0.3ulp -> O(1) pillars land one cell off (the 2.62 bug).
__device__ __forceinline__ int cell_of(float xc, float yc) {
  int xg = (int)floorf((xc + 22.0f) * 6.25f);
  int yg = (int)floorf((yc + 22.0f) * 6.25f);
  xg = min(max(xg, 0), Ww - 1);
  yg = min(max(yg, 0), Hh - 1);
  return yg * Ww + xg;
}

__device__ __forceinline__ float firstlane(float v) {
  return __int_as_float(__builtin_amdgcn_readfirstlane(__float_as_int(v)));
}
}

__global__ void kdiag(float* __restrict__ out, float v) {
  if (threadIdx.x == 0 && blockIdx.x == 0) out[0] = v;
}

__global__ void k0_init(int* __restrict__ winners, int* __restrict__ hdr) {
  const int stride = gridDim.x * blockDim.x;
  const int t = blockIdx.x * blockDim.x + threadIdx.x;
  if (t < 4) hdr[t] = 0;
  for (int i = t; i < 2 * Bn * NCELL; i += stride) winners[i] = -1;
}

// Merged over both inputs: blocks [0,K1B) -> sweep, [K1B,2*K1B) -> map.
// Memory-bound streaming pass; pillar->cell scatter fused in (lane 0 already
// holds xc/yc): one atomicMax per pillar.
__global__ __launch_bounds__(256) void k1_mom(
    const float* __restrict__ sweep, const float* __restrict__ map_in,
    float* __restrict__ partOut, int* __restrict__ winners)
{
  __shared__ float red[4][44];
  const int lane = threadIdx.x & 63;
  const int wv   = threadIdx.x >> 6;
  const int bid2 = blockIdx.x & (K1B - 1);
  const int inp  = blockIdx.x / K1B;
  const float* x = inp ? map_in : sweep;
  int* win = winners + inp * Bn * NCELL;
  const int gw   = (bid2 * 256 + (int)threadIdx.x) >> 6;
  const int nw   = (K1B * 256) >> 6;

  float sacc[8];
  float macc[36];
#pragma unroll
  for (int i = 0; i < 8; ++i) sacc[i] = 0.f;
#pragma unroll
  for (int i = 0; i < 36; ++i) macc[i] = 0.f;

  for (int pp = gw; pp < NPIL; pp += nw) {
    const int b = pp / Pn;
    const int p = pp - b * Pn;
    const float* xb = x + (size_t)b * Cin * CHW + (size_t)p * Nn + lane;
    float xv[Cin];
#pragma unroll
    for (int c = 0; c < Cin; ++c) xv[c] = xb[(size_t)c * CHW];
#pragma unroll
    for (int c = 0; c < Cin; ++c) sacc[c] += xv[c];
    {
      int k = 0;
#pragma unroll
      for (int i = 0; i < 8; ++i)
#pragma unroll
        for (int j = i; j < 8; ++j) { macc[k] = fmaf(xv[i], xv[j], macc[k]); ++k; }
    }
    // Fused scatter: xc = x[base] = lane 0's xv[0], yc = lane 0's xv[1].
    const float xc = firstlane(xv[0]);
    if (xc != 0.0f) {
      const float yc = firstlane(xv[1]);
      if (lane == 0) atomicMax(&win[b * NCELL + cell_of(xc, yc)], p);
    }
  }

#pragma unroll
  for (int k = 0; k < 44; ++k) {
    float v = (k < 8) ? sacc[k] : macc[k - 8];
#pragma unroll
    for (int off = 32; off > 0; off >>= 1) v += __shfl_down(v, off, 64);
    if (lane == 0) red[wv][k] = v;
  }
  __syncthreads();
  if (threadIdx.x < 44) {
    const float s = red[0][threadIdx.x] + red[1][threadIdx.x] +
                    red[2][threadIdx.x] + red[3][threadIdx.x];
    partOut[(size_t)bid2 * 88 + inp * 44 + threadIdx.x] = s;
  }
}

// One block per moment component; 256-thread tree reduction in double.
// (Double-precision sum: association order change is ~1e-16 relative, far
// below the f32 pipeline's tolerance.)
__global__ __launch_bounds__(256) void k1b_reduce(
    const float* __restrict__ part, double* __restrict__ mom)
{
  __shared__ double sd[256];
  const int t = blockIdx.x;              // 0..87
  double s = 0.0;
  for (int blk = threadIdx.x; blk < K1B; blk += 256)
    s += (double)part[(size_t)blk * 88 + t];
  sd[threadIdx.x] = s;
  __syncthreads();
  for (int off = 128; off > 0; off >>= 1) {
    if (threadIdx.x < off) sd[threadIdx.x] += sd[threadIdx.x + off];
    __syncthreads();
  }
  if (threadIdx.x == 0) mom[t] = sd[0];
}

// LN folded all the way into the PFN weights (double precision):
//   z[o] = sum_c (a*w[o][c]) * x[c]  +  (beta + a*(bias - mean))
// par layout per input: awc[64*8] then zb[64]  (576 floats).
__global__ void k2_params(const double* __restrict__ mom,
    const float* __restrict__ w_s, const float* __restrict__ b_s,
    const float* __restrict__ g_s, const float* __restrict__ be_s,
    const float* __restrict__ w_m, const float* __restrict__ b_m,
    const float* __restrict__ g_m, const float* __restrict__ be_m,
    float* __restrict__ par)
{
  const int t = threadIdx.x;
  if (t >= 128) return;
  const int inp = t >> 6, o = t & 63;
  const double* m = mom + inp * 44;
  const float* w    = (inp ? w_m : w_s) + o * Cin;
  const float bias  = (inp ? b_m : b_s)[o];
  const float gamma = (inp ? g_m : g_s)[o];
  const float beta  = (inp ? be_m : be_s)[o];
  double S[8];
#pragma unroll
  for (int c = 0; c < 8; ++c) S[c] = m[c] / CNTD;
  double mean = (double)bias;
#pragma unroll
  for (int c = 0; c < 8; ++c) mean += (double)w[c] * S[c];
  double var = 0.0;
  int k = 8;
#pragma unroll
  for (int i = 0; i < 8; ++i)
#pragma unroll
    for (int j = i; j < 8; ++j) {
      const double cov = m[k] / CNTD - S[i] * S[j];
      const double ww = (double)w[i] * (double)w[j];
      var += (i == j ? ww : 2.0 * ww) * cov;
      ++k;
    }
  const double a = (double)gamma / sqrt(var + 1e-5);
  float* pr = par + inp * 576;
#pragma unroll
  for (int c = 0; c < 8; ++c) pr[o * 8 + c] = (float)(a * (double)w[c]);
  pr[512 + o] = (float)((double)beta + a * ((double)bias - mean));
}

// Build packed worklists of occupied cells, BLOCK-ORDERED: per-block ballot
// scan + a single atomicAdd per block per list, so consecutive wl entries are
// consecutive cells of one 256-cell tile -> k_apply's stores stay tile-local.
// hdr[1]/hdr[2] counts double as the occupancy diagnostic.
__global__ __launch_bounds__(256) void k_compact(
    const int* __restrict__ winners, int* __restrict__ hdr,
    int2* __restrict__ wlS, int2* __restrict__ wlM)
{
  __shared__ int wcnt[2][4];
  __shared__ int base[2];
  const int t = blockIdx.x * 256 + threadIdx.x;
  const int lane = threadIdx.x & 63;
  const int wv   = threadIdx.x >> 6;
  int ps = -1, pm = -1, outbase = 0, b = 0;
  if (t < Bn * NCELL) {
    b = t / NCELL;
    const int hw = t - b * NCELL;
    outbase = b * Co * NCELL + hw;
    ps = winners[t];
    pm = winners[Bn * NCELL + t];
  }
  const unsigned long long ms = __ballot(ps >= 0);
  const unsigned long long mm = __ballot(pm >= 0);
  if (lane == 0) { wcnt[0][wv] = __popcll(ms); wcnt[1][wv] = __popcll(mm); }
  __syncthreads();
  if (threadIdx.x == 0) {
    const int c = wcnt[0][0] + wcnt[0][1] + wcnt[0][2] + wcnt[0][3];
    base[0] = c ? atomicAdd(&hdr[1], c) : 0;
  } else if (threadIdx.x == 64) {
    const int c = wcnt[1][0] + wcnt[1][1] + wcnt[1][2] + wcnt[1][3];
    base[1] = c ? atomicAdd(&hdr[2], c) : 0;
  }
  __syncthreads();
  const unsigned long long below = (1ull << lane) - 1ull;
  if (ps >= 0) {
    int off = base[0] + __popcll(ms & below);
    for (int w2 = 0; w2 < wv; ++w2) off += wcnt[0][w2];
    wlS[off] = make_int2(outbase, b * Pn + ps);
  }
  if (pm >= 0) {
    int off = base[1] + __popcll(mm & below);
    for (int w2 = 0; w2 < wv; ++w2) off += wcnt[1][w2];
    wlM[off] = make_int2(outbase, b * Pn + pm);
  }
}

// Transposed PFN, chunked: one pillar per wave, lane = point index n.
// xv[c] is lane-local -> the channel loop is pure fma with wave-uniform
// (scalar) operands: no broadcasts at all. Channels processed 8 at a time;
// after each chunk a reduce-scatter max (xor 1,2,4 halving items, then
// xor 8,16,32 folds) lands channel 8g+(lane&7) on every lane; lane keeps it
// when lane>>3 == g. Live set ~30 VGPR (the R3 z[64] version spilled at 48).
// fmax is exact under reordering -> same feature values.
__global__ __launch_bounds__(256) void k5f_feat(
    const float* __restrict__ sweep, const float* __restrict__ map_in,
    const float* __restrict__ par, const int* __restrict__ winners,
    float* __restrict__ feats)
{
  const int lane = threadIdx.x & 63;       // = n
  const int wv   = threadIdx.x >> 6;
  int pp = blockIdx.x * 4 + wv;
  const int inp = (pp >= NPIL) ? 1 : 0;
  pp -= inp * NPIL;
  const float* x   = inp ? map_in : sweep;
  const float* aw  = par + inp * 576;
  const float* zbp = aw + 512;
  const int*   win = winners + inp * Bn * NCELL;
  float*       ft  = feats + (size_t)inp * NPIL * 64;

  const int b = pp / Pn;
  const int p = pp - b * Pn;
  const size_t base = (size_t)b * Cin * CHW + (size_t)p * Nn;

  float xv[Cin];
#pragma unroll
  for (int c = 0; c < Cin; ++c) xv[c] = x[base + (size_t)c * CHW + lane];

  const float xc0 = firstlane(xv[0]);
  if (xc0 == 0.0f) return;
  const float yc0 = firstlane(xv[1]);
  const int cell = cell_of(xc0, yc0);
  if (win[b * NCELL + cell] != p) return;

  const int l0 = lane & 1, l1 = (lane >> 1) & 1, l2 = (lane >> 2) & 1;
  float res = 0.f;
  for (int g = 0; g < 8; ++g) {
    float z[8];
#pragma unroll
    for (int j = 0; j < 8; ++j) {
      const int o = g * 8 + j;
      float y = zbp[o];
#pragma unroll
      for (int c = 0; c < Cin; ++c) y = fmaf(aw[o * 8 + c], xv[c], y);
      z[j] = y;
    }
    // item-halving rounds: slot ends holding item j = lane&7
    float t0[4];
#pragma unroll
    for (int i = 0; i < 4; ++i) {
      const float send = l0 ? z[2 * i] : z[2 * i + 1];
      const float keep = l0 ? z[2 * i + 1] : z[2 * i];
      t0[i] = fmaxf(keep, __shfl_xor(send, 1, 64));
    }
    float t1[2];
#pragma unroll
    for (int i = 0; i < 2; ++i) {
      const float send = l1 ? t0[2 * i] : t0[2 * i + 1];
      const float keep = l1 ? t0[2 * i + 1] : t0[2 * i];
      t1[i] = fmaxf(keep, __shfl_xor(send, 2, 64));
    }
    {
      const float send = l2 ? t1[0] : t1[1];
      const float keep = l2 ? t1[1] : t1[0];
      float v = fmaxf(keep, __shfl_xor(send, 4, 64));
      // fold over lane groups
      v = fmaxf(v, __shfl_xor(v, 8, 64));
      v = fmaxf(v, __shfl_xor(v, 16, 64));
      v = fmaxf(v, __shfl_xor(v, 32, 64));
      if ((lane >> 3) == g) res = v;
    }
  }
  ft[(size_t)pp * 64 + lane] = fmaxf(res, 0.f);
}

// Fill the whole output with bias (pure coalesced float4 writes).
__global__ __launch_bounds__(256) void k_fill(const float* __restrict__ b_bb,
                                              float* __restrict__ out)
{
  const int idx = blockIdx.x * 256 + threadIdx.x;
  const int plane = idx / (NCELL / 4);      // b*Co + o
  const float v = b_bb[plane & 63];
  ((float4*)out)[idx] = make_float4(v, v, v, v);
}

// Dense matvec over the compacted worklist.
// WHICH=0 (sweep): out[o] = bias[o] + W[:,0:64]·f   (overwrite after k_fill)
// WHICH=1 (map):   out[o] +=          W[:,64:128]·f (RMW, runs after WHICH=0)
// fmaf ordering identical to the original fused kernel -> bit-identical.
template<int WHICH>
__global__ __launch_bounds__(256) void k_apply(
    const int* __restrict__ hdr, const int2* __restrict__ wl,
    const float* __restrict__ feats, const float* __restrict__ w_bb,
    const float* __restrict__ b_bb, float* __restrict__ out)
{
  __shared__ float4 wlds[Co * 16];
  __shared__ float bbb[Co];
  for (int i = threadIdx.x; i < Co * 16; i += 256)
    wlds[i] = ((const float4*)w_bb)[((i >> 4) << 5) + (WHICH ? 16 : 0) + (i & 15)];
  if (threadIdx.x < Co) bbb[threadIdx.x] = b_bb[threadIdx.x];
  __syncthreads();
  const int cnt = hdr[1 + WHICH];
  for (int i = blockIdx.x * blockDim.x + threadIdx.x; i < cnt;
       i += gridDim.x * blockDim.x) {
    const int2 e = wl[i];
    const float4* fp = (const float4*)(feats + (size_t)e.y * 64);
    float4 f[16];
#pragma unroll
    for (int k = 0; k < 16; ++k) f[k] = fp[k];
    float* op = out + e.x;
#pragma unroll 2
    for (int o = 0; o < Co; ++o) {
      float acc = WHICH ? op[(size_t)o * NCELL] : bbb[o];
      const float4* row = &wlds[o * 16];
#pragma unroll
      for (int k = 0; k < 16; ++k) {
        const float4 w4 = row[k];
        acc = fmaf(w4.x, f[k].x, acc); acc = fmaf(w4.y, f[k].y, acc);
        acc = fmaf(w4.z, f[k].z, acc); acc = fmaf(w4.w, f[k].w, acc);
      }
      op[(size_t)o * NCELL] = acc;
    }
  }
}

__global__ void k6_verdict(const int* __restrict__ hdr, float* __restrict__ out)
{
  if (threadIdx.x != 0 || blockIdx.x != 0) return;
  const int n_occ = hdr[1] + hdr[2];
  if (n_occ < 80000 || n_occ > 96000) out[0] = 1.0e7f + (float)n_occ;
}

extern "C" void kernel_launch(void* const* d_in, const int* in_sizes, int n_in,
                              void* d_out, int out_size, void* d_ws, size_t ws_size,
                              hipStream_t stream)
{
  const float* sweep  = (const float*)d_in[0];
  const float* map_in = (const float*)d_in[1];
  const float* w_s  = (const float*)d_in[2];
  const float* b_s  = (const float*)d_in[3];
  const float* g_s  = (const float*)d_in[4];
  const float* be_s = (const float*)d_in[5];
  const float* w_m  = (const float*)d_in[6];
  const float* b_m  = (const float*)d_in[7];
  const float* g_m  = (const float*)d_in[8];
  const float* be_m = (const float*)d_in[9];
  const float* w_bb = (const float*)d_in[10];
  const float* b_bb = (const float*)d_in[11];
  float* out = (float*)d_out;

  const int exp_sz[12] = {24576000, 24576000, 512, 64, 64, 64, 512, 64, 64, 64, 8192, 64};
  int bad_idx = -1;
  if (n_in != 12) bad_idx = 11;
  else for (int i = 0; i < 12; ++i) if (in_sizes[i] != exp_sz[i]) { bad_idx = i; break; }
  if (bad_idx >= 0) {
    kdiag<<<1, 1, 0, stream>>>(out, 9.0e7f + 1.0e5f * (float)bad_idx);
    return;
  }
  if (ws_size < WS_NEED) {
    kdiag<<<1, 1, 0, stream>>>(out, 8.0e7f);
    return;
  }

  char* ws = (char*)d_ws;
  float*  par     = (float*)(ws + PAR_OFF);
  double* mom     = (double*)(ws + MOM_OFF);
  int*    hdr     = (int*)(ws + HDR_OFF);
  int*    winners = (int*)(ws + WIN_OFF);
  float*  feats   = (float*)(ws + FEAT_OFF);
  float*  part    = (float*)(ws + PART_OFF);
  int2*   wlS     = (int2*)(ws + WLS_OFF);
  int2*   wlM     = (int2*)(ws + WLM_OFF);

  k0_init<<<512, 256, 0, stream>>>(winners, hdr);
  k_fill<<<(Bn * Co * NCELL / 4) / 256, 256, 0, stream>>>(b_bb, out);
  k1_mom<<<2 * K1B, 256, 0, stream>>>(sweep, map_in, part, winners);
  k1b_reduce<<<88, 256, 0, stream>>>(part, mom);
  k2_params<<<1, 128, 0, stream>>>(mom, w_s, b_s, g_s, be_s, w_m, b_m, g_m, be_m, par);
  k_compact<<<(Bn * NCELL + 255) / 256, 256, 0, stream>>>(winners, hdr, wlS, wlM);
  k5f_feat<<<2 * NPIL / 4, 256, 0, stream>>>(sweep, map_in, par, winners, feats);
  k_apply<0><<<APPLY_B, 256, 0, stream>>>(hdr, wlS, feats, w_bb, b_bb, out);
  k_apply<1><<<APPLY_B, 256, 0, stream>>>(hdr, wlM, feats + (size_t)NPIL * 64,
                                          w_bb, b_bb, out);
  k6_verdict<<<1, 1, 0, stream>>>(hdr, out);
}

// Round 5
// 327.854 us; speedup vs baseline: 2.3785x; 1.7321x over previous
//
#include <hip/hip_runtime.h>
#include <cfloat>
#include <math.h>

namespace {
constexpr int Bn = 4, Cin = 8, Pn = 12000, Nn = 64, Co = 64, Hh = 282, Ww = 282;
constexpr int NPIL  = Bn * Pn;
constexpr int NCELL = Hh * Ww;
constexpr int CHW   = Pn * Nn;
constexpr double CNTD = (double)Bn * Pn * Nn;
constexpr int K1B = 1024;               // k1_mom blocks per input (8 waves/SIMD)
constexpr int WL_CAP = 48000;           // max occupied cells per input
constexpr int APPLY_B = (WL_CAP + 255) / 256;

// Workspace layout. part (k1_mom partials) aliases the feats region: it is
// dead after k1b_reduce, before k5f_feat writes feats.
constexpr size_t PAR_OFF  = 0;                          // 2*576 floats = 4608
constexpr size_t MOM_OFF  = 4608;                       // 88 doubles   = 704
constexpr size_t HDR_OFF  = 5376;                       // 4 ints
constexpr size_t WLS_OFF  = 8192;                       // WL_CAP int2
constexpr size_t WLM_OFF  = WLS_OFF + (size_t)WL_CAP * 8;
constexpr size_t WIN_OFF  = WLM_OFF + (size_t)WL_CAP * 8;   // 776192
constexpr size_t FEAT_OFF = WIN_OFF + (size_t)2 * Bn * NCELL * 4; // 3320960
constexpr size_t PART_OFF = FEAT_OFF;                   // alias (see above)
constexpr size_t WS_NEED  = FEAT_OFF + (size_t)2 * NPIL * 64 * 4; // 27896960

typedef __attribute__((ext_vector_type(16))) float f32x16_t;
typedef __attribute__((ext_vector_type(4)))  float f32x4_t;

// Grid mapping matched to XLA's canonicalization: division by 0.16 becomes
// multiplication by the EXACT reciprocal 6.25 (rcp(0.16f) rounds to 6.25f).
// f32-div differs by ~0.3ulp -> O(1) pillars land one cell off (the 2.62 bug).
__device__ __forceinline__ int cell_of(float xc, float yc) {
  int xg = (int)floorf((xc + 22.0f) * 6.25f);
  int yg = (int)floorf((yc + 22.0f) * 6.25f);
  xg = min(max(xg, 0), Ww - 1);
  yg = min(max(yg, 0), Hh - 1);
  return yg * Ww + xg;
}

__device__ __forceinline__ float firstlane(float v) {
  return __int_as_float(__builtin_amdgcn_readfirstlane(__float_as_int(v)));
}
}

__global__ void kdiag(float* __restrict__ out, float v) {
  if (threadIdx.x == 0 && blockIdx.x == 0) out[0] = v;
}

__global__ void k0_init(int* __restrict__ winners, int* __restrict__ hdr) {
  const int stride = gridDim.x * blockDim.x;
  const int t = blockIdx.x * blockDim.x + threadIdx.x;
  if (t < 4) hdr[t] = 0;
  for (int i = t; i < 2 * Bn * NCELL; i += stride) winners[i] = -1;
}

// Merged over both inputs: blocks [0,K1B) -> sweep, [K1B,2*K1B) -> map.
// Memory-bound streaming pass; pillar->cell scatter fused in (lane 0 already
// holds xc/yc): one atomicMax per pillar.
__global__ __launch_bounds__(256) void k1_mom(
    const float* __restrict__ sweep, const float* __restrict__ map_in,
    float* __restrict__ partOut, int* __restrict__ winners)
{
  __shared__ float red[4][44];
  const int lane = threadIdx.x & 63;
  const int wv   = threadIdx.x >> 6;
  const int bid2 = blockIdx.x & (K1B - 1);
  const int inp  = blockIdx.x / K1B;
  const float* x = inp ? map_in : sweep;
  int* win = winners + inp * Bn * NCELL;
  const int gw   = (bid2 * 256 + (int)threadIdx.x) >> 6;
  const int nw   = (K1B * 256) >> 6;

  float sacc[8];
  float macc[36];
#pragma unroll
  for (int i = 0; i < 8; ++i) sacc[i] = 0.f;
#pragma unroll
  for (int i = 0; i < 36; ++i) macc[i] = 0.f;

  for (int pp = gw; pp < NPIL; pp += nw) {
    const int b = pp / Pn;
    const int p = pp - b * Pn;
    const float* xb = x + (size_t)b * Cin * CHW + (size_t)p * Nn + lane;
    float xv[Cin];
#pragma unroll
    for (int c = 0; c < Cin; ++c) xv[c] = xb[(size_t)c * CHW];
#pragma unroll
    for (int c = 0; c < Cin; ++c) sacc[c] += xv[c];
    {
      int k = 0;
#pragma unroll
      for (int i = 0; i < 8; ++i)
#pragma unroll
        for (int j = i; j < 8; ++j) { macc[k] = fmaf(xv[i], xv[j], macc[k]); ++k; }
    }
    // Fused scatter: xc = x[base] = lane 0's xv[0], yc = lane 0's xv[1].
    const float xc = firstlane(xv[0]);
    if (xc != 0.0f) {
      const float yc = firstlane(xv[1]);
      if (lane == 0) atomicMax(&win[b * NCELL + cell_of(xc, yc)], p);
    }
  }

#pragma unroll
  for (int k = 0; k < 44; ++k) {
    float v = (k < 8) ? sacc[k] : macc[k - 8];
#pragma unroll
    for (int off = 32; off > 0; off >>= 1) v += __shfl_down(v, off, 64);
    if (lane == 0) red[wv][k] = v;
  }
  __syncthreads();
  if (threadIdx.x < 44) {
    const float s = red[0][threadIdx.x] + red[1][threadIdx.x] +
                    red[2][threadIdx.x] + red[3][threadIdx.x];
    partOut[(size_t)bid2 * 88 + inp * 44 + threadIdx.x] = s;
  }
}

// One block per moment component; 256-thread tree reduction in double.
__global__ __launch_bounds__(256) void k1b_reduce(
    const float* __restrict__ part, double* __restrict__ mom)
{
  __shared__ double sd[256];
  const int t = blockIdx.x;              // 0..87
  double s = 0.0;
  for (int blk = threadIdx.x; blk < K1B; blk += 256)
    s += (double)part[(size_t)blk * 88 + t];
  sd[threadIdx.x] = s;
  __syncthreads();
  for (int off = 128; off > 0; off >>= 1) {
    if (threadIdx.x < off) sd[threadIdx.x] += sd[threadIdx.x + off];
    __syncthreads();
  }
  if (threadIdx.x == 0) mom[t] = sd[0];
}

// LN folded all the way into the PFN weights (double precision):
//   z[o] = sum_c (a*w[o][c]) * x[c]  +  (beta + a*(bias - mean))
// par layout per input: awc[64*8] then zb[64]  (576 floats).
__global__ void k2_params(const double* __restrict__ mom,
    const float* __restrict__ w_s, const float* __restrict__ b_s,
    const float* __restrict__ g_s, const float* __restrict__ be_s,
    const float* __restrict__ w_m, const float* __restrict__ b_m,
    const float* __restrict__ g_m, const float* __restrict__ be_m,
    float* __restrict__ par)
{
  const int t = threadIdx.x;
  if (t >= 128) return;
  const int inp = t >> 6, o = t & 63;
  const double* m = mom + inp * 44;
  const float* w    = (inp ? w_m : w_s) + o * Cin;
  const float bias  = (inp ? b_m : b_s)[o];
  const float gamma = (inp ? g_m : g_s)[o];
  const float beta  = (inp ? be_m : be_s)[o];
  double S[8];
#pragma unroll
  for (int c = 0; c < 8; ++c) S[c] = m[c] / CNTD;
  double mean = (double)bias;
#pragma unroll
  for (int c = 0; c < 8; ++c) mean += (double)w[c] * S[c];
  double var = 0.0;
  int k = 8;
#pragma unroll
  for (int i = 0; i < 8; ++i)
#pragma unroll
    for (int j = i; j < 8; ++j) {
      const double cov = m[k] / CNTD - S[i] * S[j];
      const double ww = (double)w[i] * (double)w[j];
      var += (i == j ? ww : 2.0 * ww) * cov;
      ++k;
    }
  const double a = (double)gamma / sqrt(var + 1e-5);
  float* pr = par + inp * 576;
#pragma unroll
  for (int c = 0; c < 8; ++c) pr[o * 8 + c] = (float)(a * (double)w[c]);
  pr[512 + o] = (float)((double)beta + a * ((double)bias - mean));
}

// Build packed worklists of occupied cells, BLOCK-ORDERED: per-block ballot
// scan + a single atomicAdd per block per list, so consecutive wl entries are
// consecutive cells of one 256-cell tile -> k_apply's stores stay tile-local.
// hdr[1]/hdr[2] counts double as the occupancy diagnostic.
__global__ __launch_bounds__(256) void k_compact(
    const int* __restrict__ winners, int* __restrict__ hdr,
    int2* __restrict__ wlS, int2* __restrict__ wlM)
{
  __shared__ int wcnt[2][4];
  __shared__ int base[2];
  const int t = blockIdx.x * 256 + threadIdx.x;
  const int lane = threadIdx.x & 63;
  const int wv   = threadIdx.x >> 6;
  int ps = -1, pm = -1, outbase = 0, b = 0;
  if (t < Bn * NCELL) {
    b = t / NCELL;
    const int hw = t - b * NCELL;
    outbase = b * Co * NCELL + hw;
    ps = winners[t];
    pm = winners[Bn * NCELL + t];
  }
  const unsigned long long ms = __ballot(ps >= 0);
  const unsigned long long mm = __ballot(pm >= 0);
  if (lane == 0) { wcnt[0][wv] = __popcll(ms); wcnt[1][wv] = __popcll(mm); }
  __syncthreads();
  if (threadIdx.x == 0) {
    const int c = wcnt[0][0] + wcnt[0][1] + wcnt[0][2] + wcnt[0][3];
    base[0] = c ? atomicAdd(&hdr[1], c) : 0;
  } else if (threadIdx.x == 64) {
    const int c = wcnt[1][0] + wcnt[1][1] + wcnt[1][2] + wcnt[1][3];
    base[1] = c ? atomicAdd(&hdr[2], c) : 0;
  }
  __syncthreads();
  const unsigned long long below = (1ull << lane) - 1ull;
  if (ps >= 0) {
    int off = base[0] + __popcll(ms & below);
    for (int w2 = 0; w2 < wv; ++w2) off += wcnt[0][w2];
    wlS[off] = make_int2(outbase, b * Pn + ps);
  }
  if (pm >= 0) {
    int off = base[1] + __popcll(mm & below);
    for (int w2 = 0; w2 < wv; ++w2) off += wcnt[1][w2];
    wlM[off] = make_int2(outbase, b * Pn + pm);
  }
}

// Transposed PFN, chunked, with weights delivered via EXPLICIT SMEM loads.
// One pillar per wave, lane = point index n: xv[c] is lane-local (no
// broadcasts). Channels 8 at a time; per half-chunk (4 channels) a single
// inline-asm block does 2x s_load_dwordx16 + 1x s_load_dwordx4 + waitcnt,
// putting the 36 weight floats in SGPRs (scalar-cache hits: 4.6KB table
// shared by all waves). The inner loop is then pure v_fma_f32 with one
// scalar operand -- no VMEM weight loads on the critical path (the R4
// bottleneck: SGPR_Count=32 showed weights went through VMEM).
// Load+wait in ONE asm block => consumers are SSA-ordered after the wait.
// fma chain (y=zb, c ascending) and fmax tree identical to R4 -> bit-identical.
__global__ __launch_bounds__(256) void k5f_feat(
    const float* __restrict__ sweep, const float* __restrict__ map_in,
    const float* __restrict__ par, const int* __restrict__ winners,
    float* __restrict__ feats)
{
  const int lane = threadIdx.x & 63;       // = n
  const int wv   = __builtin_amdgcn_readfirstlane(threadIdx.x >> 6);
  int pp = blockIdx.x * 4 + wv;
  const int inp = (pp >= NPIL) ? 1 : 0;
  pp -= inp * NPIL;
  const float* x   = inp ? map_in : sweep;
  const float* aw  = par + inp * 576;
  const float* zbp = aw + 512;
  const int*   win = winners + inp * Bn * NCELL;
  float*       ft  = feats + (size_t)inp * NPIL * 64;

  const int b = pp / Pn;
  const int p = pp - b * Pn;
  const size_t base = (size_t)b * Cin * CHW + (size_t)p * Nn;

  float xv[Cin];
#pragma unroll
  for (int c = 0; c < Cin; ++c) xv[c] = x[base + (size_t)c * CHW + lane];

  const float xc0 = firstlane(xv[0]);
  if (xc0 == 0.0f) return;
  const float yc0 = firstlane(xv[1]);
  const int cell = cell_of(xc0, yc0);
  if (win[b * NCELL + cell] != p) return;

  const int l0 = lane & 1, l1 = (lane >> 1) & 1, l2 = (lane >> 2) & 1;
  float res = 0.f;
#pragma unroll
  for (int g = 0; g < 8; ++g) {
    float z[8];
#pragma unroll
    for (int h = 0; h < 2; ++h) {
      f32x16_t w0, w1;
      f32x4_t  zb4;
      asm("s_load_dwordx16 %0, %3, 0x0\n\t"
          "s_load_dwordx16 %1, %3, 0x40\n\t"
          "s_load_dwordx4  %2, %4, 0x0\n\t"
          "s_waitcnt lgkmcnt(0)"
          : "=&s"(w0), "=&s"(w1), "=&s"(zb4)
          : "s"(aw + g * 64 + h * 32), "s"(zbp + g * 8 + h * 4));
#pragma unroll
      for (int j = 0; j < 4; ++j) {
        float y = zb4[j];
#pragma unroll
        for (int c = 0; c < Cin; ++c) {
          const float wgt = (j < 2) ? w0[j * 8 + c] : w1[(j - 2) * 8 + c];
          y = fmaf(wgt, xv[c], y);
        }
        z[h * 4 + j] = y;
      }
    }
    // item-halving rounds: slot ends holding item j = lane&7
    float t0[4];
#pragma unroll
    for (int i = 0; i < 4; ++i) {
      const float send = l0 ? z[2 * i] : z[2 * i + 1];
      const float keep = l0 ? z[2 * i + 1] : z[2 * i];
      t0[i] = fmaxf(keep, __shfl_xor(send, 1, 64));
    }
    float t1[2];
#pragma unroll
    for (int i = 0; i < 2; ++i) {
      const float send = l1 ? t0[2 * i] : t0[2 * i + 1];
      const float keep = l1 ? t0[2 * i + 1] : t0[2 * i];
      t1[i] = fmaxf(keep, __shfl_xor(send, 2, 64));
    }
    {
      const float send = l2 ? t1[0] : t1[1];
      const float keep = l2 ? t1[1] : t1[0];
      float v = fmaxf(keep, __shfl_xor(send, 4, 64));
      // fold over lane groups
      v = fmaxf(v, __shfl_xor(v, 8, 64));
      v = fmaxf(v, __shfl_xor(v, 16, 64));
      v = fmaxf(v, __shfl_xor(v, 32, 64));
      if ((lane >> 3) == g) res = v;
    }
  }
  ft[(size_t)pp * 64 + lane] = fmaxf(res, 0.f);
}

// Fill the whole output with bias (pure coalesced float4 writes).
__global__ __launch_bounds__(256) void k_fill(const float* __restrict__ b_bb,
                                              float* __restrict__ out)
{
  const int idx = blockIdx.x * 256 + threadIdx.x;
  const int plane = idx / (NCELL / 4);      // b*Co + o
  const float v = b_bb[plane & 63];
  ((float4*)out)[idx] = make_float4(v, v, v, v);
}

// Dense matvec over the compacted worklist.
// WHICH=0 (sweep): out[o] = bias[o] + W[:,0:64]·f   (overwrite after k_fill)
// WHICH=1 (map):   out[o] +=          W[:,64:128]·f (RMW, runs after WHICH=0)
// fmaf ordering identical to the original fused kernel -> bit-identical.
template<int WHICH>
__global__ __launch_bounds__(256) void k_apply(
    const int* __restrict__ hdr, const int2* __restrict__ wl,
    const float* __restrict__ feats, const float* __restrict__ w_bb,
    const float* __restrict__ b_bb, float* __restrict__ out)
{
  __shared__ float4 wlds[Co * 16];
  __shared__ float bbb[Co];
  for (int i = threadIdx.x; i < Co * 16; i += 256)
    wlds[i] = ((const float4*)w_bb)[((i >> 4) << 5) + (WHICH ? 16 : 0) + (i & 15)];
  if (threadIdx.x < Co) bbb[threadIdx.x] = b_bb[threadIdx.x];
  __syncthreads();
  const int cnt = hdr[1 + WHICH];
  for (int i = blockIdx.x * blockDim.x + threadIdx.x; i < cnt;
       i += gridDim.x * blockDim.x) {
    const int2 e = wl[i];
    const float4* fp = (const float4*)(feats + (size_t)e.y * 64);
    float4 f[16];
#pragma unroll
    for (int k = 0; k < 16; ++k) f[k] = fp[k];
    float* op = out + e.x;
#pragma unroll 2
    for (int o = 0; o < Co; ++o) {
      float acc = WHICH ? op[(size_t)o * NCELL] : bbb[o];
      const float4* row = &wlds[o * 16];
#pragma unroll
      for (int k = 0; k < 16; ++k) {
        const float4 w4 = row[k];
        acc = fmaf(w4.x, f[k].x, acc); acc = fmaf(w4.y, f[k].y, acc);
        acc = fmaf(w4.z, f[k].z, acc); acc = fmaf(w4.w, f[k].w, acc);
      }
      op[(size_t)o * NCELL] = acc;
    }
  }
}

__global__ void k6_verdict(const int* __restrict__ hdr, float* __restrict__ out)
{
  if (threadIdx.x != 0 || blockIdx.x != 0) return;
  const int n_occ = hdr[1] + hdr[2];
  if (n_occ < 80000 || n_occ > 96000) out[0] = 1.0e7f + (float)n_occ;
}

extern "C" void kernel_launch(void* const* d_in, const int* in_sizes, int n_in,
                              void* d_out, int out_size, void* d_ws, size_t ws_size,
                              hipStream_t stream)
{
  const float* sweep  = (const float*)d_in[0];
  const float* map_in = (const float*)d_in[1];
  const float* w_s  = (const float*)d_in[2];
  const float* b_s  = (const float*)d_in[3];
  const float* g_s  = (const float*)d_in[4];
  const float* be_s = (const float*)d_in[5];
  const float* w_m  = (const float*)d_in[6];
  const float* b_m  = (const float*)d_in[7];
  const float* g_m  = (const float*)d_in[8];
  const float* be_m = (const float*)d_in[9];
  const float* w_bb = (const float*)d_in[10];
  const float* b_bb = (const float*)d_in[11];
  float* out = (float*)d_out;

  const int exp_sz[12] = {24576000, 24576000, 512, 64, 64, 64, 512, 64, 64, 64, 8192, 64};
  int bad_idx = -1;
  if (n_in != 12) bad_idx = 11;
  else for (int i = 0; i < 12; ++i) if (in_sizes[i] != exp_sz[i]) { bad_idx = i; break; }
  if (bad_idx >= 0) {
    kdiag<<<1, 1, 0, stream>>>(out, 9.0e7f + 1.0e5f * (float)bad_idx);
    return;
  }
  if (ws_size < WS_NEED) {
    kdiag<<<1, 1, 0, stream>>>(out, 8.0e7f);
    return;
  }

  char* ws = (char*)d_ws;
  float*  par     = (float*)(ws + PAR_OFF);
  double* mom     = (double*)(ws + MOM_OFF);
  int*    hdr     = (int*)(ws + HDR_OFF);
  int*    winners = (int*)(ws + WIN_OFF);
  float*  feats   = (float*)(ws + FEAT_OFF);
  float*  part    = (float*)(ws + PART_OFF);
  int2*   wlS     = (int2*)(ws + WLS_OFF);
  int2*   wlM     = (int2*)(ws + WLM_OFF);

  k0_init<<<512, 256, 0, stream>>>(winners, hdr);
  k_fill<<<(Bn * Co * NCELL / 4) / 256, 256, 0, stream>>>(b_bb, out);
  k1_mom<<<2 * K1B, 256, 0, stream>>>(sweep, map_in, part, winners);
  k1b_reduce<<<88, 256, 0, stream>>>(part, mom);
  k2_params<<<1, 128, 0, stream>>>(mom, w_s, b_s, g_s, be_s, w_m, b_m, g_m, be_m, par);
  k_compact<<<(Bn * NCELL + 255) / 256, 256, 0, stream>>>(winners, hdr, wlS, wlM);
  k5f_feat<<<2 * NPIL / 4, 256, 0, stream>>>(sweep, map_in, par, winners, feats);
  k_apply<0><<<APPLY_B, 256, 0, stream>>>(hdr, wlS, feats, w_bb, b_bb, out);
  k_apply<1><<<APPLY_B, 256, 0, stream>>>(hdr, wlM, feats + (size_t)NPIL * 64,
                                          w_bb, b_bb, out);
  k6_verdict<<<1, 1, 0, stream>>>(hdr, out);
}